// Round 1
// baseline (2183.147 us; speedup 1.0000x reference)
//
#include <hip/hip_runtime.h>
#include <hip/hip_bf16.h>

// Problem constants
#define D_MODEL 256
#define D_INNER 512
#define NHEADS 8
#define HEADDIM 64
#define MDIST 16
#define BB 4
#define LL 2048
#define QQ 300
#define QP 320          // padded Q (8 waves * 40)
#define NSEG 16
#define SEGLEN 128      // LL / NSEG
#define TN 40           // n-slice per wave

// ---------------------------------------------------------------------------
// Generic fp32 GEMM:  C[M,N] = A[M,K] (row-major) * B[N,K]^T (row-major, NT)
// K must be a multiple of 16.
// ---------------------------------------------------------------------------
__global__ __launch_bounds__(256) void gemm_nt(const float* __restrict__ A,
                                               const float* __restrict__ B,
                                               float* __restrict__ C,
                                               int M, int N, int K) {
    __shared__ float As[16][64 + 4];
    __shared__ float Bs[16][64 + 4];
    int m0 = blockIdx.y * 64, n0 = blockIdx.x * 64;
    int tid = threadIdx.x;
    int tx = tid % 16, ty = tid / 16;  // tx: n, ty: m
    float acc[4][4] = {};
    for (int k0 = 0; k0 < K; k0 += 16) {
        int r = tid >> 2;             // 0..63
        int c4 = (tid & 3) * 4;       // 0,4,8,12
        int m = m0 + r;
        float4 va = make_float4(0.f, 0.f, 0.f, 0.f);
        if (m < M) va = *(const float4*)(A + (size_t)m * K + k0 + c4);
        As[c4 + 0][r] = va.x; As[c4 + 1][r] = va.y;
        As[c4 + 2][r] = va.z; As[c4 + 3][r] = va.w;
        int n = n0 + r;
        float4 vb = make_float4(0.f, 0.f, 0.f, 0.f);
        if (n < N) vb = *(const float4*)(B + (size_t)n * K + k0 + c4);
        Bs[c4 + 0][r] = vb.x; Bs[c4 + 1][r] = vb.y;
        Bs[c4 + 2][r] = vb.z; Bs[c4 + 3][r] = vb.w;
        __syncthreads();
#pragma unroll
        for (int k = 0; k < 16; k++) {
            float a[4], b[4];
#pragma unroll
            for (int i = 0; i < 4; i++) a[i] = As[k][ty * 4 + i];
#pragma unroll
            for (int j = 0; j < 4; j++) b[j] = Bs[k][tx * 4 + j];
#pragma unroll
            for (int i = 0; i < 4; i++)
#pragma unroll
                for (int j = 0; j < 4; j++) acc[i][j] = fmaf(a[i], b[j], acc[i][j]);
        }
        __syncthreads();
    }
#pragma unroll
    for (int i = 0; i < 4; i++) {
        int m = m0 + ty * 4 + i;
        if (m >= M) continue;
#pragma unroll
        for (int j = 0; j < 4; j++) {
            int n = n0 + tx * 4 + j;
            if (n < N) C[(size_t)m * N + n] = acc[i][j];
        }
    }
}

// ---------------------------------------------------------------------------
// K2: dist (B,L,Q,16) -> dA (B,L,H,QP), dtB (B,L,H,QP), Cm (B,L,QP)
// ---------------------------------------------------------------------------
__global__ __launch_bounds__(256) void k2_dist(const float* __restrict__ dist,
                                               const float* __restrict__ zx,
                                               const float* __restrict__ W_bc,
                                               const float* __restrict__ W_dt,
                                               const float* __restrict__ dt_bias,
                                               const float* __restrict__ A_log,
                                               float* __restrict__ dA,
                                               float* __restrict__ dtB,
                                               float* __restrict__ Cm) {
    __shared__ float sWbc[32], sWdt[128], sb[8], sA[8];
    int tid = threadIdx.x;
    if (tid < 32) sWbc[tid] = W_bc[tid];
    else if (tid < 160) sWdt[tid - 32] = W_dt[tid - 32];
    else if (tid < 168) sb[tid - 160] = dt_bias[tid - 160];
    else if (tid < 176) sA[tid - 168] = -expf(A_log[tid - 168]);
    __syncthreads();
    int gid = blockIdx.x * 256 + tid;          // (b*L + l)*Q + q
    if (gid >= BB * LL * QQ) return;
    int q = gid % QQ;
    int bl = gid / QQ;
    const float* dp = dist + (size_t)gid * 16;
    float d[16];
    float4 d0 = *(const float4*)(dp + 0);
    float4 d1 = *(const float4*)(dp + 4);
    float4 d2 = *(const float4*)(dp + 8);
    float4 d3 = *(const float4*)(dp + 12);
    d[0]=d0.x; d[1]=d0.y; d[2]=d0.z; d[3]=d0.w;
    d[4]=d1.x; d[5]=d1.y; d[6]=d1.z; d[7]=d1.w;
    d[8]=d2.x; d[9]=d2.y; d[10]=d2.z; d[11]=d2.w;
    d[12]=d3.x; d[13]=d3.y; d[14]=d3.z; d[15]=d3.w;
    float bc0 = 0.f, bc1 = 0.f;
#pragma unroll
    for (int m = 0; m < 16; m++) {
        bc0 = fmaf(d[m], sWbc[m], bc0);
        bc1 = fmaf(d[m], sWbc[16 + m], bc1);
    }
    int zrow = bl * 1034;
    float Bmv = bc0 + zx[zrow + 1024];
    float Cv  = bc1 + zx[zrow + 1025];
    Cm[bl * QP + q] = Cv;
#pragma unroll
    for (int h = 0; h < 8; h++) {
        float t = 0.f;
#pragma unroll
        for (int m = 0; m < 16; m++) t = fmaf(d[m], sWdt[h * 16 + m], t);
        float pre = t + zx[zrow + 1026 + h] + sb[h];
        float dt = (pre > 20.f) ? pre : log1pf(expf(pre));
        int o = (bl * 8 + h) * QP + q;
        dA[o]  = expf(sA[h] * dt);
        dtB[o] = dt * Bmv;
    }
}

// ---------------------------------------------------------------------------
// K2b: per-segment decay product  segd (B,NSEG,H,QP)
// ---------------------------------------------------------------------------
__global__ __launch_bounds__(256) void k2b_segdecay(const float* __restrict__ dA,
                                                    float* __restrict__ segd) {
    int gid = blockIdx.x * 256 + threadIdx.x;   // ((b*16+s)*8+h)*QP+q
    if (gid >= BB * NSEG * 8 * QP) return;
    int q = gid % QP; int r = gid / QP;
    int h = r % 8; r /= 8;
    int s = r % NSEG; int b = r / NSEG;
    int base = ((b * LL + s * SEGLEN) * 8 + h) * QP + q;
    float p = 1.f;
    for (int i = 0; i < SEGLEN; i++) p *= dA[base + i * 8 * QP];
    segd[gid] = p;
}

// ---------------------------------------------------------------------------
// Pass A: segment-local state march (S_in = 0), writes S_local
// grid: (NSEG, B*H, 2), block 512 (8 waves x 64 lanes=p)
// ---------------------------------------------------------------------------
__global__ __launch_bounds__(512) void pass_a(const float* __restrict__ dA,
                                              const float* __restrict__ dtB,
                                              const float* __restrict__ zx,
                                              float* __restrict__ S_local) {
    int seg = blockIdx.x, bh = blockIdx.y, dir = blockIdx.z;
    int w = threadIdx.x >> 6, lane = threadIdx.x & 63;
    int n0 = w * TN;
    int b = bh >> 3, h = bh & 7;
    float S[TN];
#pragma unroll
    for (int j = 0; j < TN; j++) S[j] = 0.f;
    for (int i = 0; i < SEGLEN; i++) {
        int l = dir ? (LL - 1 - (seg * SEGLEN + i)) : (seg * SEGLEN + i);
        int bl = b * LL + l;
        int ob = (bl * 8 + h) * QP + n0;
        const float* __restrict__ pA = dA + ob;
        const float* __restrict__ pB = dtB + ob;
        float x = zx[bl * 1034 + 512 + h * 64 + lane];
#pragma unroll
        for (int j = 0; j < TN; j++) S[j] = fmaf(S[j], pA[j], pB[j] * x);
    }
    int base = (((dir * NSEG + seg) * 32 + bh) * QP + n0) * 64 + lane;
#pragma unroll
    for (int j = 0; j < TN; j++) S_local[base + j * 64] = S[j];
}

// ---------------------------------------------------------------------------
// Pass B: sequential segment combine (16 steps), writes S_in per segment and
// the averaged final state Savg (B,H,QP,P)
// ---------------------------------------------------------------------------
__global__ __launch_bounds__(256) void pass_b(const float* __restrict__ S_local,
                                              const float* __restrict__ segd,
                                              const float* __restrict__ S0q,
                                              float* __restrict__ S_in,
                                              float* __restrict__ Savg) {
    int gid = blockIdx.x * 256 + threadIdx.x;   // (b,h,n,p)
    if (gid >= BB * 8 * QP * 64) return;
    int p = gid & 63; int r = gid >> 6;
    int n = r % QP; r /= QP;
    int h = r & 7; int b = r >> 3;
    int bh = b * 8 + h;
    float s0 = (n < QQ) ? S0q[(size_t)(b * QQ + n) * 512 + h * 64 + p] : 0.f;
    float Sf = 0.f, Sb = 0.f;
    for (int dir = 0; dir < 2; dir++) {
        float S = s0;
        for (int s = 0; s < NSEG; s++) {
            int idx = (((dir * NSEG + s) * 32 + bh) * QP + n) * 64 + p;
            S_in[idx] = S;
            int sf = dir ? (NSEG - 1 - s) : s;
            float dec = segd[((b * NSEG + sf) * 8 + h) * QP + n];
            S = fmaf(S, dec, S_local[idx]);
        }
        if (dir == 0) Sf = S; else Sb = S;
    }
    Savg[((bh) * QP + n) * 64 + p] = 0.5f * (Sf + Sb);
}

// ---------------------------------------------------------------------------
// Pass C: replay with true S_in, compute y (without Dp*x), write y_f / y_b
// ---------------------------------------------------------------------------
__global__ __launch_bounds__(512) void pass_c(const float* __restrict__ dA,
                                              const float* __restrict__ dtB,
                                              const float* __restrict__ Cm,
                                              const float* __restrict__ zx,
                                              const float* __restrict__ S_in,
                                              float* __restrict__ yf,
                                              float* __restrict__ yb) {
    __shared__ float red[2][8][64];
    int seg = blockIdx.x, bh = blockIdx.y, dir = blockIdx.z;
    int w = threadIdx.x >> 6, lane = threadIdx.x & 63;
    int n0 = w * TN;
    int b = bh >> 3, h = bh & 7;
    float S[TN];
    int sbase = (((dir * NSEG + seg) * 32 + bh) * QP + n0) * 64 + lane;
#pragma unroll
    for (int j = 0; j < TN; j++) S[j] = S_in[sbase + j * 64];
    float* __restrict__ yo = dir ? yb : yf;
    for (int i = 0; i < SEGLEN; i++) {
        int l = dir ? (LL - 1 - (seg * SEGLEN + i)) : (seg * SEGLEN + i);
        int bl = b * LL + l;
        int ob = (bl * 8 + h) * QP + n0;
        const float* __restrict__ pA = dA + ob;
        const float* __restrict__ pB = dtB + ob;
        const float* __restrict__ pC = Cm + bl * QP + n0;
        float x = zx[bl * 1034 + 512 + h * 64 + lane];
        float y = 0.f;
#pragma unroll
        for (int j = 0; j < TN; j++) {
            S[j] = fmaf(S[j], pA[j], pB[j] * x);
            y = fmaf(S[j], pC[j], y);
        }
        red[i & 1][w][lane] = y;
        __syncthreads();
        if (w == (i & 7)) {
            float t = 0.f;
#pragma unroll
            for (int ww = 0; ww < 8; ww++) t += red[i & 1][ww][lane];
            yo[(bl * 8 + h) * 64 + lane] = t;
        }
    }
}

// ---------------------------------------------------------------------------
// K4: y = 0.5*(yf+yb) + Dp*x ; g = y*silu(z) ; key = g * rms(g) * key_norm_w
// one block per (b,l), 512 threads
// ---------------------------------------------------------------------------
__global__ __launch_bounds__(512) void k4_gate(const float* __restrict__ yf,
                                               const float* __restrict__ yb,
                                               const float* __restrict__ zx,
                                               const float* __restrict__ Dp,
                                               const float* __restrict__ knw,
                                               float* __restrict__ key) {
    int bl = blockIdx.x;
    int t = threadIdx.x;
    int h = t >> 6;
    int zrow = bl * 1034;
    float x = zx[zrow + 512 + t];
    float yv = 0.5f * (yf[bl * 512 + t] + yb[bl * 512 + t]) + Dp[h] * x;
    float z = zx[zrow + t];
    float g = yv * (z / (1.f + expf(-z)));
    float v = g * g;
#pragma unroll
    for (int o = 32; o > 0; o >>= 1) v += __shfl_down(v, o, 64);
    __shared__ float rs[8];
    __shared__ float stot;
    if ((t & 63) == 0) rs[t >> 6] = v;
    __syncthreads();
    if (t == 0) {
        float s = 0.f;
#pragma unroll
        for (int i = 0; i < 8; i++) s += rs[i];
        stot = s;
    }
    __syncthreads();
    float rms = rsqrtf(stot / 512.f + 1e-5f);
    key[(size_t)bl * 512 + t] = g * rms * knw[t];
}

// ---------------------------------------------------------------------------
// K5: layernorm on Savg rearranged to (B,Q,512); one block per (b,q)
// ---------------------------------------------------------------------------
__global__ __launch_bounds__(512) void k5_ln(const float* __restrict__ Savg,
                                             const float* __restrict__ lnw,
                                             const float* __restrict__ lnb,
                                             float* __restrict__ lsn) {
    int bq = blockIdx.x;
    int b = bq / QQ, q = bq % QQ;
    int t = threadIdx.x;
    int h = t >> 6, p = t & 63;
    float v = Savg[((b * 8 + h) * QP + q) * 64 + p];
    float s1 = v, s2 = v * v;
#pragma unroll
    for (int o = 32; o > 0; o >>= 1) {
        s1 += __shfl_down(s1, o, 64);
        s2 += __shfl_down(s2, o, 64);
    }
    __shared__ float r1[8], r2[8];
    __shared__ float smu, srv;
    if ((t & 63) == 0) { r1[t >> 6] = s1; r2[t >> 6] = s2; }
    __syncthreads();
    if (t == 0) {
        float a = 0.f, c = 0.f;
#pragma unroll
        for (int i = 0; i < 8; i++) { a += r1[i]; c += r2[i]; }
        float mu = a / 512.f;
        float var = c / 512.f - mu * mu;
        smu = mu;
        srv = rsqrtf(var + 1e-5f);
    }
    __syncthreads();
    lsn[(size_t)bq * 512 + t] = (v - smu) * srv * lnw[t] + lnb[t];
}

// ---------------------------------------------------------------------------
extern "C" void kernel_launch(void* const* d_in, const int* in_sizes, int n_in,
                              void* d_out, int out_size, void* d_ws, size_t ws_size,
                              hipStream_t stream) {
    const float* in_key    = (const float*)d_in[0];
    const float* in_query  = (const float*)d_in[1];
    const float* dist      = (const float*)d_in[2];
    const float* W_key     = (const float*)d_in[3];
    const float* W_query   = (const float*)d_in[4];
    const float* W_bc      = (const float*)d_in[5];
    const float* W_dt      = (const float*)d_in[6];
    const float* dt_bias   = (const float*)d_in[7];
    const float* A_log     = (const float*)d_in[8];
    const float* Dp        = (const float*)d_in[9];
    const float* W_out_key = (const float*)d_in[10];
    const float* W_out_query = (const float*)d_in[11];
    const float* key_norm_w = (const float*)d_in[12];
    const float* ln_w      = (const float*)d_in[13];
    const float* ln_b      = (const float*)d_in[14];

    float* out_key = (float*)d_out;
    float* out_query = out_key + (size_t)BB * LL * D_MODEL;   // 2,097,152

    float* ws = (float*)d_ws;
    float* zx   = ws; ws += (size_t)8192 * 1034;      // 8,470,528
    float* S0q  = ws; ws += (size_t)1200 * 512;       //   614,400
    float* dAb  = ws; ws += (size_t)8192 * 8 * QP;    // 20,971,520
    float* dtBb = ws; ws += (size_t)8192 * 8 * QP;    // 20,971,520
    float* Cmb  = ws; ws += (size_t)8192 * QP;        //  2,621,440
    float* segd = ws; ws += (size_t)BB * NSEG * 8 * QP; // 163,840
    float* Sloc = ws; ws += (size_t)2 * NSEG * 32 * QP * 64; // 20,971,520
    float* Sin  = ws; ws += (size_t)2 * NSEG * 32 * QP * 64; // 20,971,520
    float* yfb  = ws; ws += (size_t)8192 * 512;       // 4,194,304
    float* ybb  = ws; ws += (size_t)8192 * 512;       // 4,194,304
    float* Savg = ws; ws += (size_t)32 * QP * 64;     //   655,360
    float* keyb = ws; ws += (size_t)8192 * 512;       // 4,194,304
    float* lsn  = ws; ws += (size_t)1200 * 512;       //   614,400

    // Projections
    gemm_nt<<<dim3(17, 128), 256, 0, stream>>>(in_key, W_key, zx, 8192, 1034, 256);
    gemm_nt<<<dim3(8, 19), 256, 0, stream>>>(in_query, W_query, S0q, 1200, 512, 256);
    // dist -> dA, dtB, Cm
    k2_dist<<<9600, 256, 0, stream>>>(dist, zx, W_bc, W_dt, dt_bias, A_log, dAb, dtBb, Cmb);
    k2b_segdecay<<<640, 256, 0, stream>>>(dAb, segd);
    // 3-pass segmented bidirectional scan
    pass_a<<<dim3(NSEG, 32, 2), 512, 0, stream>>>(dAb, dtBb, zx, Sloc);
    pass_b<<<2560, 256, 0, stream>>>(Sloc, segd, S0q, Sin, Savg);
    pass_c<<<dim3(NSEG, 32, 2), 512, 0, stream>>>(dAb, dtBb, Cmb, zx, Sin, yfb, ybb);
    // out_key path
    k4_gate<<<8192, 512, 0, stream>>>(yfb, ybb, zx, Dp, key_norm_w, keyb);
    gemm_nt<<<dim3(4, 128), 256, 0, stream>>>(keyb, W_out_key, out_key, 8192, 256, 512);
    // out_query path
    k5_ln<<<1200, 512, 0, stream>>>(Savg, ln_w, ln_b, lsn);
    gemm_nt<<<dim3(4, 19), 256, 0, stream>>>(lsn, W_out_query, out_query, 1200, 256, 512);
}

// Round 2
// 1093.545 us; speedup vs baseline: 1.9964x; 1.9964x over previous
//
#include <hip/hip_runtime.h>
#include <hip/hip_bf16.h>

// Problem constants
#define D_MODEL 256
#define D_INNER 512
#define NHEADS 8
#define HEADDIM 64
#define MDIST 16
#define BB 4
#define LL 2048
#define QQ 300
#define QP 320          // padded Q (8 waves * 40)
#define NSEG 16
#define SEGLEN 128      // LL / NSEG
#define TN 40           // n-slice per wave

// ---------------------------------------------------------------------------
// Generic fp32 GEMM:  C[M,N] = A[M,K] (row-major) * B[N,K]^T (row-major, NT)
// K must be a multiple of 16.
// ---------------------------------------------------------------------------
__global__ __launch_bounds__(256) void gemm_nt(const float* __restrict__ A,
                                               const float* __restrict__ B,
                                               float* __restrict__ C,
                                               int M, int N, int K) {
    __shared__ float As[16][64 + 4];
    __shared__ float Bs[16][64 + 4];
    int m0 = blockIdx.y * 64, n0 = blockIdx.x * 64;
    int tid = threadIdx.x;
    int tx = tid % 16, ty = tid / 16;  // tx: n, ty: m
    float acc[4][4] = {};
    for (int k0 = 0; k0 < K; k0 += 16) {
        int r = tid >> 2;             // 0..63
        int c4 = (tid & 3) * 4;       // 0,4,8,12
        int m = m0 + r;
        float4 va = make_float4(0.f, 0.f, 0.f, 0.f);
        if (m < M) va = *(const float4*)(A + (size_t)m * K + k0 + c4);
        As[c4 + 0][r] = va.x; As[c4 + 1][r] = va.y;
        As[c4 + 2][r] = va.z; As[c4 + 3][r] = va.w;
        int n = n0 + r;
        float4 vb = make_float4(0.f, 0.f, 0.f, 0.f);
        if (n < N) vb = *(const float4*)(B + (size_t)n * K + k0 + c4);
        Bs[c4 + 0][r] = vb.x; Bs[c4 + 1][r] = vb.y;
        Bs[c4 + 2][r] = vb.z; Bs[c4 + 3][r] = vb.w;
        __syncthreads();
#pragma unroll
        for (int k = 0; k < 16; k++) {
            float a[4], b[4];
#pragma unroll
            for (int i = 0; i < 4; i++) a[i] = As[k][ty * 4 + i];
#pragma unroll
            for (int j = 0; j < 4; j++) b[j] = Bs[k][tx * 4 + j];
#pragma unroll
            for (int i = 0; i < 4; i++)
#pragma unroll
                for (int j = 0; j < 4; j++) acc[i][j] = fmaf(a[i], b[j], acc[i][j]);
        }
        __syncthreads();
    }
#pragma unroll
    for (int i = 0; i < 4; i++) {
        int m = m0 + ty * 4 + i;
        if (m >= M) continue;
#pragma unroll
        for (int j = 0; j < 4; j++) {
            int n = n0 + tx * 4 + j;
            if (n < N) C[(size_t)m * N + n] = acc[i][j];
        }
    }
}

// ---------------------------------------------------------------------------
// K2: dist (B,L,Q,16) -> dA (B,L,H,QP), dtB (B,L,H,QP), Cm (B,L,QP)
// ---------------------------------------------------------------------------
__global__ __launch_bounds__(256) void k2_dist(const float* __restrict__ dist,
                                               const float* __restrict__ zx,
                                               const float* __restrict__ W_bc,
                                               const float* __restrict__ W_dt,
                                               const float* __restrict__ dt_bias,
                                               const float* __restrict__ A_log,
                                               float* __restrict__ dA,
                                               float* __restrict__ dtB,
                                               float* __restrict__ Cm) {
    __shared__ float sWbc[32], sWdt[128], sb[8], sA[8];
    int tid = threadIdx.x;
    if (tid < 32) sWbc[tid] = W_bc[tid];
    else if (tid < 160) sWdt[tid - 32] = W_dt[tid - 32];
    else if (tid < 168) sb[tid - 160] = dt_bias[tid - 160];
    else if (tid < 176) sA[tid - 168] = -expf(A_log[tid - 168]);
    __syncthreads();
    int gid = blockIdx.x * 256 + tid;          // (b*L + l)*Q + q
    if (gid >= BB * LL * QQ) return;
    int q = gid % QQ;
    int bl = gid / QQ;
    const float* dp = dist + (size_t)gid * 16;
    float d[16];
    float4 d0 = *(const float4*)(dp + 0);
    float4 d1 = *(const float4*)(dp + 4);
    float4 d2 = *(const float4*)(dp + 8);
    float4 d3 = *(const float4*)(dp + 12);
    d[0]=d0.x; d[1]=d0.y; d[2]=d0.z; d[3]=d0.w;
    d[4]=d1.x; d[5]=d1.y; d[6]=d1.z; d[7]=d1.w;
    d[8]=d2.x; d[9]=d2.y; d[10]=d2.z; d[11]=d2.w;
    d[12]=d3.x; d[13]=d3.y; d[14]=d3.z; d[15]=d3.w;
    float bc0 = 0.f, bc1 = 0.f;
#pragma unroll
    for (int m = 0; m < 16; m++) {
        bc0 = fmaf(d[m], sWbc[m], bc0);
        bc1 = fmaf(d[m], sWbc[16 + m], bc1);
    }
    int zrow = bl * 1034;
    float Bmv = bc0 + zx[zrow + 1024];
    float Cv  = bc1 + zx[zrow + 1025];
    Cm[bl * QP + q] = Cv;
#pragma unroll
    for (int h = 0; h < 8; h++) {
        float t = 0.f;
#pragma unroll
        for (int m = 0; m < 16; m++) t = fmaf(d[m], sWdt[h * 16 + m], t);
        float pre = t + zx[zrow + 1026 + h] + sb[h];
        float dt = (pre > 20.f) ? pre : log1pf(expf(pre));
        int o = (bl * 8 + h) * QP + q;
        dA[o]  = expf(sA[h] * dt);
        dtB[o] = dt * Bmv;
    }
}

// ---------------------------------------------------------------------------
// K2b: per-segment decay product  segd (B,NSEG,H,QP)
// ---------------------------------------------------------------------------
__global__ __launch_bounds__(256) void k2b_segdecay(const float* __restrict__ dA,
                                                    float* __restrict__ segd) {
    int gid = blockIdx.x * 256 + threadIdx.x;   // ((b*16+s)*8+h)*QP+q
    if (gid >= BB * NSEG * 8 * QP) return;
    int q = gid % QP; int r = gid / QP;
    int h = r % 8; r /= 8;
    int s = r % NSEG; int b = r / NSEG;
    int base = ((b * LL + s * SEGLEN) * 8 + h) * QP + q;
    float p = 1.f;
    for (int i = 0; i < SEGLEN; i++) p *= dA[base + i * 8 * QP];
    segd[gid] = p;
}

// ---------------------------------------------------------------------------
// Pass A: segment-local state march (S_in = 0), writes S_local
// grid: (NSEG, B*H, 2), block 512 (8 waves x 64 lanes=p)
// Operands staged cooperatively in double-buffered LDS:
//   layout per buffer: [dA 0..319 | dtB 320..639 | x 640..703]  (704 floats)
// ---------------------------------------------------------------------------
__global__ __launch_bounds__(512, 1) void pass_a(const float* __restrict__ dA,
                                                 const float* __restrict__ dtB,
                                                 const float* __restrict__ zx,
                                                 float* __restrict__ S_local) {
    __shared__ float sOp[2][704];
    int seg = blockIdx.x, bh = blockIdx.y, dir = blockIdx.z;
    int tid = threadIdx.x;
    int w = tid >> 6, lane = tid & 63;
    int n0 = w * TN;
    int b = bh >> 3, h = bh & 7;
    float S[TN];
#pragma unroll
    for (int j = 0; j < TN; j++) S[j] = 0.f;

    // stage iteration 0
    {
        int l = dir ? (LL - 1 - seg * SEGLEN) : (seg * SEGLEN);
        int bl = b * LL + l;
        if (tid < 352) {
            const float2* src;
            if (tid < 160)      src = (const float2*)(dA  + (size_t)(bl * 8 + h) * QP) + tid;
            else if (tid < 320) src = (const float2*)(dtB + (size_t)(bl * 8 + h) * QP) + (tid - 160);
            else                src = (const float2*)(zx + (size_t)bl * 1034 + 512 + h * 64) + (tid - 320);
            ((float2*)sOp[0])[tid] = *src;
        }
    }

    for (int i = 0; i < SEGLEN; i++) {
        __syncthreads();
        // stage next iteration into the other buffer
        if (i + 1 < SEGLEN && tid < 352) {
            int l = dir ? (LL - 1 - (seg * SEGLEN + i + 1)) : (seg * SEGLEN + i + 1);
            int bl = b * LL + l;
            const float2* src;
            if (tid < 160)      src = (const float2*)(dA  + (size_t)(bl * 8 + h) * QP) + tid;
            else if (tid < 320) src = (const float2*)(dtB + (size_t)(bl * 8 + h) * QP) + (tid - 160);
            else                src = (const float2*)(zx + (size_t)bl * 1034 + 512 + h * 64) + (tid - 320);
            ((float2*)sOp[(i + 1) & 1])[tid] = *src;
        }
        // compute iteration i from current buffer
        const float* bufc = sOp[i & 1];
        float x = bufc[640 + lane];
#pragma unroll
        for (int c = 0; c < 10; c++) {
            float4 a4 = *(const float4*)(bufc + n0 + c * 4);
            float4 b4 = *(const float4*)(bufc + 320 + n0 + c * 4);
            S[c * 4 + 0] = fmaf(S[c * 4 + 0], a4.x, b4.x * x);
            S[c * 4 + 1] = fmaf(S[c * 4 + 1], a4.y, b4.y * x);
            S[c * 4 + 2] = fmaf(S[c * 4 + 2], a4.z, b4.z * x);
            S[c * 4 + 3] = fmaf(S[c * 4 + 3], a4.w, b4.w * x);
        }
    }
    int base = (((dir * NSEG + seg) * 32 + bh) * QP + n0) * 64 + lane;
#pragma unroll
    for (int j = 0; j < TN; j++) S_local[base + j * 64] = S[j];
}

// ---------------------------------------------------------------------------
// Pass B: sequential segment combine (16 steps), writes S_in per segment and
// the averaged final state Savg (B,H,QP,P)
// ---------------------------------------------------------------------------
__global__ __launch_bounds__(256) void pass_b(const float* __restrict__ S_local,
                                              const float* __restrict__ segd,
                                              const float* __restrict__ S0q,
                                              float* __restrict__ S_in,
                                              float* __restrict__ Savg) {
    int gid = blockIdx.x * 256 + threadIdx.x;   // (b,h,n,p)
    if (gid >= BB * 8 * QP * 64) return;
    int p = gid & 63; int r = gid >> 6;
    int n = r % QP; r /= QP;
    int h = r & 7; int b = r >> 3;
    int bh = b * 8 + h;
    float s0 = (n < QQ) ? S0q[(size_t)(b * QQ + n) * 512 + h * 64 + p] : 0.f;
    float Sf = 0.f, Sb = 0.f;
    for (int dir = 0; dir < 2; dir++) {
        float S = s0;
        for (int s = 0; s < NSEG; s++) {
            int idx = (((dir * NSEG + s) * 32 + bh) * QP + n) * 64 + p;
            S_in[idx] = S;
            int sf = dir ? (NSEG - 1 - s) : s;
            float dec = segd[((b * NSEG + sf) * 8 + h) * QP + n];
            S = fmaf(S, dec, S_local[idx]);
        }
        if (dir == 0) Sf = S; else Sb = S;
    }
    Savg[((bh) * QP + n) * 64 + p] = 0.5f * (Sf + Sb);
}

// ---------------------------------------------------------------------------
// Pass C: replay with true S_in, compute y (without Dp*x), write y_f / y_b
// Operand LDS layout per buffer: [dA 0..319 | dtB 320..639 | Cm 640..959 |
// x 960..1023] (1024 floats). y partial reduction via double-buffered LDS,
// one barrier per timestep total.
// ---------------------------------------------------------------------------
__global__ __launch_bounds__(512, 1) void pass_c(const float* __restrict__ dA,
                                                 const float* __restrict__ dtB,
                                                 const float* __restrict__ Cm,
                                                 const float* __restrict__ zx,
                                                 const float* __restrict__ S_in,
                                                 float* __restrict__ yf,
                                                 float* __restrict__ yb) {
    __shared__ float sOp[2][1024];
    __shared__ float ybuf[2][8][8][64];   // [buf][slot=i&7][wave][lane]
    int seg = blockIdx.x, bh = blockIdx.y, dir = blockIdx.z;
    int tid = threadIdx.x;
    int w = tid >> 6, lane = tid & 63;
    int n0 = w * TN;
    int b = bh >> 3, h = bh & 7;
    float S[TN];
    int sbase = (((dir * NSEG + seg) * 32 + bh) * QP + n0) * 64 + lane;
#pragma unroll
    for (int j = 0; j < TN; j++) S[j] = S_in[sbase + j * 64];
    float* __restrict__ yo = dir ? yb : yf;

    // stage iteration 0
    {
        int l = dir ? (LL - 1 - seg * SEGLEN) : (seg * SEGLEN);
        int bl = b * LL + l;
        const float2* src;
        if (tid < 160)      src = (const float2*)(dA  + (size_t)(bl * 8 + h) * QP) + tid;
        else if (tid < 320) src = (const float2*)(dtB + (size_t)(bl * 8 + h) * QP) + (tid - 160);
        else if (tid < 480) src = (const float2*)(Cm + (size_t)bl * QP) + (tid - 320);
        else                src = (const float2*)(zx + (size_t)bl * 1034 + 512 + h * 64) + (tid - 480);
        ((float2*)sOp[0])[tid] = *src;
    }

    for (int i = 0; i < SEGLEN; i++) {
        __syncthreads();
        // reduce the completed 8-block (iters i-8..i-1); its buffer differs
        // from the one being written this 8-block, so no extra barrier.
        if ((i & 7) == 0 && i != 0) {
            int it = i - 8 + w;
            int l = dir ? (LL - 1 - (seg * SEGLEN + it)) : (seg * SEGLEN + it);
            int bl = b * LL + l;
            const float* yb0 = &ybuf[((i >> 3) & 1) ^ 1][w][0][lane];
            float t = 0.f;
#pragma unroll
            for (int ww = 0; ww < 8; ww++) t += yb0[ww * 64];
            yo[(bl * 8 + h) * 64 + lane] = t;
        }
        // stage next iteration
        if (i + 1 < SEGLEN) {
            int l = dir ? (LL - 1 - (seg * SEGLEN + i + 1)) : (seg * SEGLEN + i + 1);
            int bl = b * LL + l;
            const float2* src;
            if (tid < 160)      src = (const float2*)(dA  + (size_t)(bl * 8 + h) * QP) + tid;
            else if (tid < 320) src = (const float2*)(dtB + (size_t)(bl * 8 + h) * QP) + (tid - 160);
            else if (tid < 480) src = (const float2*)(Cm + (size_t)bl * QP) + (tid - 320);
            else                src = (const float2*)(zx + (size_t)bl * 1034 + 512 + h * 64) + (tid - 480);
            ((float2*)sOp[(i + 1) & 1])[tid] = *src;
        }
        // compute iteration i
        const float* bufc = sOp[i & 1];
        float x = bufc[960 + lane];
        float y = 0.f;
#pragma unroll
        for (int c = 0; c < 10; c++) {
            float4 a4 = *(const float4*)(bufc + n0 + c * 4);
            float4 b4 = *(const float4*)(bufc + 320 + n0 + c * 4);
            float4 c4 = *(const float4*)(bufc + 640 + n0 + c * 4);
            S[c * 4 + 0] = fmaf(S[c * 4 + 0], a4.x, b4.x * x); y = fmaf(S[c * 4 + 0], c4.x, y);
            S[c * 4 + 1] = fmaf(S[c * 4 + 1], a4.y, b4.y * x); y = fmaf(S[c * 4 + 1], c4.y, y);
            S[c * 4 + 2] = fmaf(S[c * 4 + 2], a4.z, b4.z * x); y = fmaf(S[c * 4 + 2], c4.z, y);
            S[c * 4 + 3] = fmaf(S[c * 4 + 3], a4.w, b4.w * x); y = fmaf(S[c * 4 + 3], c4.w, y);
        }
        ybuf[(i >> 3) & 1][i & 7][w][lane] = y;
    }
    __syncthreads();
    // final reduction: block 15 lives in buffer 1
    {
        int it = SEGLEN - 8 + w;
        int l = dir ? (LL - 1 - (seg * SEGLEN + it)) : (seg * SEGLEN + it);
        int bl = b * LL + l;
        const float* yb0 = &ybuf[1][w][0][lane];
        float t = 0.f;
#pragma unroll
        for (int ww = 0; ww < 8; ww++) t += yb0[ww * 64];
        yo[(bl * 8 + h) * 64 + lane] = t;
    }
}

// ---------------------------------------------------------------------------
// K4: y = 0.5*(yf+yb) + Dp*x ; g = y*silu(z) ; key = g * rms(g) * key_norm_w
// one block per (b,l), 512 threads
// ---------------------------------------------------------------------------
__global__ __launch_bounds__(512) void k4_gate(const float* __restrict__ yf,
                                               const float* __restrict__ yb,
                                               const float* __restrict__ zx,
                                               const float* __restrict__ Dp,
                                               const float* __restrict__ knw,
                                               float* __restrict__ key) {
    int bl = blockIdx.x;
    int t = threadIdx.x;
    int h = t >> 6;
    int zrow = bl * 1034;
    float x = zx[zrow + 512 + t];
    float yv = 0.5f * (yf[bl * 512 + t] + yb[bl * 512 + t]) + Dp[h] * x;
    float z = zx[zrow + t];
    float g = yv * (z / (1.f + expf(-z)));
    float v = g * g;
#pragma unroll
    for (int o = 32; o > 0; o >>= 1) v += __shfl_down(v, o, 64);
    __shared__ float rs[8];
    __shared__ float stot;
    if ((t & 63) == 0) rs[t >> 6] = v;
    __syncthreads();
    if (t == 0) {
        float s = 0.f;
#pragma unroll
        for (int i = 0; i < 8; i++) s += rs[i];
        stot = s;
    }
    __syncthreads();
    float rms = rsqrtf(stot / 512.f + 1e-5f);
    key[(size_t)bl * 512 + t] = g * rms * knw[t];
}

// ---------------------------------------------------------------------------
// K5: layernorm on Savg rearranged to (B,Q,512); one block per (b,q)
// ---------------------------------------------------------------------------
__global__ __launch_bounds__(512) void k5_ln(const float* __restrict__ Savg,
                                             const float* __restrict__ lnw,
                                             const float* __restrict__ lnb,
                                             float* __restrict__ lsn) {
    int bq = blockIdx.x;
    int b = bq / QQ, q = bq % QQ;
    int t = threadIdx.x;
    int h = t >> 6, p = t & 63;
    float v = Savg[((b * 8 + h) * QP + q) * 64 + p];
    float s1 = v, s2 = v * v;
#pragma unroll
    for (int o = 32; o > 0; o >>= 1) {
        s1 += __shfl_down(s1, o, 64);
        s2 += __shfl_down(s2, o, 64);
    }
    __shared__ float r1[8], r2[8];
    __shared__ float smu, srv;
    if ((t & 63) == 0) { r1[t >> 6] = s1; r2[t >> 6] = s2; }
    __syncthreads();
    if (t == 0) {
        float a = 0.f, c = 0.f;
#pragma unroll
        for (int i = 0; i < 8; i++) { a += r1[i]; c += r2[i]; }
        float mu = a / 512.f;
        float var = c / 512.f - mu * mu;
        smu = mu;
        srv = rsqrtf(var + 1e-5f);
    }
    __syncthreads();
    lsn[(size_t)bq * 512 + t] = (v - smu) * srv * lnw[t] + lnb[t];
}

// ---------------------------------------------------------------------------
extern "C" void kernel_launch(void* const* d_in, const int* in_sizes, int n_in,
                              void* d_out, int out_size, void* d_ws, size_t ws_size,
                              hipStream_t stream) {
    const float* in_key    = (const float*)d_in[0];
    const float* in_query  = (const float*)d_in[1];
    const float* dist      = (const float*)d_in[2];
    const float* W_key     = (const float*)d_in[3];
    const float* W_query   = (const float*)d_in[4];
    const float* W_bc      = (const float*)d_in[5];
    const float* W_dt      = (const float*)d_in[6];
    const float* dt_bias   = (const float*)d_in[7];
    const float* A_log     = (const float*)d_in[8];
    const float* Dp        = (const float*)d_in[9];
    const float* W_out_key = (const float*)d_in[10];
    const float* W_out_query = (const float*)d_in[11];
    const float* key_norm_w = (const float*)d_in[12];
    const float* ln_w      = (const float*)d_in[13];
    const float* ln_b      = (const float*)d_in[14];

    float* out_key = (float*)d_out;
    float* out_query = out_key + (size_t)BB * LL * D_MODEL;   // 2,097,152

    float* ws = (float*)d_ws;
    float* zx   = ws; ws += (size_t)8192 * 1034;      // 8,470,528
    float* S0q  = ws; ws += (size_t)1200 * 512;       //   614,400
    float* dAb  = ws; ws += (size_t)8192 * 8 * QP;    // 20,971,520
    float* dtBb = ws; ws += (size_t)8192 * 8 * QP;    // 20,971,520
    float* Cmb  = ws; ws += (size_t)8192 * QP;        //  2,621,440
    float* segd = ws; ws += (size_t)BB * NSEG * 8 * QP; // 163,840
    float* Sloc = ws; ws += (size_t)2 * NSEG * 32 * QP * 64; // 20,971,520
    float* Sin  = ws; ws += (size_t)2 * NSEG * 32 * QP * 64; // 20,971,520
    float* yfb  = ws; ws += (size_t)8192 * 512;       // 4,194,304
    float* ybb  = ws; ws += (size_t)8192 * 512;       // 4,194,304
    float* Savg = ws; ws += (size_t)32 * QP * 64;     //   655,360
    float* keyb = ws; ws += (size_t)8192 * 512;       // 4,194,304
    float* lsn  = ws; ws += (size_t)1200 * 512;       //   614,400

    // Projections
    gemm_nt<<<dim3(17, 128), 256, 0, stream>>>(in_key, W_key, zx, 8192, 1034, 256);
    gemm_nt<<<dim3(8, 19), 256, 0, stream>>>(in_query, W_query, S0q, 1200, 512, 256);
    // dist -> dA, dtB, Cm
    k2_dist<<<9600, 256, 0, stream>>>(dist, zx, W_bc, W_dt, dt_bias, A_log, dAb, dtBb, Cmb);
    k2b_segdecay<<<640, 256, 0, stream>>>(dAb, segd);
    // 3-pass segmented bidirectional scan
    pass_a<<<dim3(NSEG, 32, 2), 512, 0, stream>>>(dAb, dtBb, zx, Sloc);
    pass_b<<<2560, 256, 0, stream>>>(Sloc, segd, S0q, Sin, Savg);
    pass_c<<<dim3(NSEG, 32, 2), 512, 0, stream>>>(dAb, dtBb, Cmb, zx, Sin, yfb, ybb);
    // out_key path
    k4_gate<<<8192, 512, 0, stream>>>(yfb, ybb, zx, Dp, key_norm_w, keyb);
    gemm_nt<<<dim3(4, 128), 256, 0, stream>>>(keyb, W_out_key, out_key, 8192, 256, 512);
    // out_query path
    k5_ln<<<1200, 512, 0, stream>>>(Savg, ln_w, ln_b, lsn);
    gemm_nt<<<dim3(4, 19), 256, 0, stream>>>(lsn, W_out_query, out_query, 1200, 256, 512);
}